// Round 8
// baseline (287.266 us; speedup 1.0000x reference)
//
#include <hip/hip_runtime.h>
#include <hip/hip_bf16.h>
#include <math.h>

#define L_SEQ 2048
#define DIM   2048
#define NH    16
#define HD    128
#define TDIM  6144

typedef __attribute__((ext_vector_type(8))) short short8;
typedef __attribute__((ext_vector_type(4))) float f32x4;
typedef __attribute__((ext_vector_type(16))) float f32x16;
typedef __attribute__((ext_vector_type(4))) unsigned int u32x4;

// async global->LDS, 16 B per lane. LDS dest = wave-uniform base + lane*16.
__device__ __forceinline__ void gl_lds16(const void* g, void* l) {
  __builtin_amdgcn_global_load_lds(
      (const __attribute__((address_space(1))) unsigned int*)g,
      (__attribute__((address_space(3))) unsigned int*)l, 16, 0, 0);
}

__device__ __forceinline__ short bf16bits(float x) {
  __hip_bfloat16 h = __float2bfloat16(x);
  return *(short*)&h;
}

__device__ __forceinline__ float bits2f(short s) {
  unsigned int u = ((unsigned int)(unsigned short)s) << 16;
  return __uint_as_float(u);
}

__device__ __forceinline__ unsigned int pack_bf16(float a, float b) {
  __hip_bfloat162 h = __float22bfloat162_rn(make_float2(a, b));
  return *(unsigned int*)&h;
}

// ---------------------------------------------------------------------------
// fused fp32 -> bf16 cast of x (4M), qkv_w (12M), proj_w (4M) in one launch.
// ---------------------------------------------------------------------------
__global__ __launch_bounds__(256)
void cast3_bf16(const float* __restrict__ a, __hip_bfloat16* __restrict__ oa,
                const float* __restrict__ b, __hip_bfloat16* __restrict__ ob,
                const float* __restrict__ c, __hip_bfloat16* __restrict__ oc) {
  int i = (blockIdx.x * 256 + threadIdx.x) * 8;
  const float* src;
  __hip_bfloat16* dst;
  int off;
  if (i < DIM * DIM)                  { src = a; dst = oa; off = i; }
  else if (i < DIM * DIM + TDIM * DIM){ src = b; dst = ob; off = i - DIM * DIM; }
  else                                { src = c; dst = oc; off = i - DIM * DIM - TDIM * DIM; }
  float4 v0 = *(const float4*)(src + off);
  float4 v1 = *(const float4*)(src + off + 4);
  short8 o;
  o[0] = bf16bits(v0.x); o[1] = bf16bits(v0.y); o[2] = bf16bits(v0.z); o[3] = bf16bits(v0.w);
  o[4] = bf16bits(v1.x); o[5] = bf16bits(v1.y); o[6] = bf16bits(v1.z); o[7] = bf16bits(v1.w);
  *(short8*)(dst + off) = o;
}

// ---------------------------------------------------------------------------
// QKV GEMM (verified R6): BM=256 x BN=192, 256 blocks = 1/CU, deep ring,
// counted per-wave vmcnt, LDS XOR swizzle, XCD 2x4 chunking.
// ---------------------------------------------------------------------------
#define QKV_N 6144
#define QKV_K 2048

__global__ __launch_bounds__(512, 2)
void gemm_qkv_256(const __hip_bfloat16* __restrict__ A,
                  const __hip_bfloat16* __restrict__ B,
                  __hip_bfloat16* __restrict__ C) {
  extern __shared__ char smem[];
  const int tid  = threadIdx.x;
  const int lane = tid & 63, w = tid >> 6;
  const int l15  = lane & 15, quad = lane >> 4;
  const int wm   = w >> 2, wn = w & 3;

  const int orig = blockIdx.x;
  const int c   = orig & 7;
  const int idx = orig >> 3;                 // 0..31
  const int by  = (c >> 2) * 4 + (idx >> 3); // 0..7
  const int bx  = (c & 3) * 8 + (idx & 7);   // 0..31
  const int m0 = by * 256, n0 = bx * 192;

  const int ar0 = tid >> 2,         aq0 = (tid & 3) ^ ((ar0 >> 1) & 3);
  const int ar1 = (512 + tid) >> 2, aq1 = (tid & 3) ^ ((ar1 >> 1) & 3);
  const __hip_bfloat16* pA0 = A + (size_t)(m0 + ar0) * QKV_K + aq0 * 8;
  const __hip_bfloat16* pA1 = A + (size_t)(m0 + ar1) * QKV_K + aq1 * 8;
  const __hip_bfloat16* pB0 = B + (size_t)(n0 + ar0) * QKV_K + aq0 * 8;
  const __hip_bfloat16* pB1 = B + (size_t)(n0 + ar1) * QKV_K + aq1 * 8;
  const int dst0 = w * 1024;

  f32x4 acc[8][3];
#pragma unroll
  for (int mi = 0; mi < 8; ++mi)
#pragma unroll
    for (int ni = 0; ni < 3; ++ni) acc[mi][ni] = (f32x4){0.f, 0.f, 0.f, 0.f};

  const int sq   = (l15 >> 1) & 3;
  const int aoff = ((wm * 128 + l15) * 32 + (quad ^ sq) * 8) * 2;
  const int boff = 16384 + ((wn * 48 + l15) * 32 + (quad ^ sq) * 8) * 2;

#pragma unroll
  for (int p = 0; p < 3; ++p) {
    char* Sp = smem + p * 28672;
    gl_lds16(pA0 + p * 32, Sp + dst0);
    gl_lds16(pA1 + p * 32, Sp + dst0 + 8192);
    gl_lds16(pB0 + p * 32, Sp + 16384 + dst0);
    if (w < 4) gl_lds16(pB1 + p * 32, Sp + 24576 + dst0);
  }
  if (w < 4) asm volatile("s_waitcnt vmcnt(8)" ::: "memory");
  else       asm volatile("s_waitcnt vmcnt(6)" ::: "memory");
  __builtin_amdgcn_s_barrier();

  for (int tb = 0; tb < 64; tb += 4) {
#pragma unroll
    for (int u = 0; u < 4; ++u) {
      const int t  = tb + u;
      const char* As = smem + (u & 3) * 28672;
      const char* Bs = As;
      const int tn = (t + 3) & 63;
      char* Sn = smem + ((u + 3) & 3) * 28672;

      short8 a[8];
#pragma unroll
      for (int mi = 0; mi < 8; ++mi)
        a[mi] = *(const short8*)(As + aoff + mi * 1024);
      short8 b0 = *(const short8*)(Bs + boff);
      short8 b1 = *(const short8*)(Bs + boff + 1024);
      gl_lds16(pA0 + tn * 32, Sn + dst0);
      gl_lds16(pA1 + tn * 32, Sn + dst0 + 8192);
      __builtin_amdgcn_s_barrier();
      __builtin_amdgcn_s_setprio(1);
#pragma unroll
      for (int mi = 0; mi < 8; ++mi) {
        acc[mi][0] = __builtin_amdgcn_mfma_f32_16x16x32_bf16(a[mi], b0, acc[mi][0], 0, 0, 0);
        acc[mi][1] = __builtin_amdgcn_mfma_f32_16x16x32_bf16(a[mi], b1, acc[mi][1], 0, 0, 0);
      }
      __builtin_amdgcn_s_setprio(0);
      __builtin_amdgcn_s_barrier();

      short8 b2 = *(const short8*)(Bs + boff + 2048);
      gl_lds16(pB0 + tn * 32, Sn + 16384 + dst0);
      if (w < 4) {
        gl_lds16(pB1 + tn * 32, Sn + 24576 + dst0);
        asm volatile("s_waitcnt vmcnt(8)" ::: "memory");
      } else {
        asm volatile("s_waitcnt vmcnt(6)" ::: "memory");
      }
      __builtin_amdgcn_s_barrier();
      __builtin_amdgcn_s_setprio(1);
#pragma unroll
      for (int mi = 0; mi < 8; ++mi)
        acc[mi][2] = __builtin_amdgcn_mfma_f32_16x16x32_bf16(a[mi], b2, acc[mi][2], 0, 0, 0);
      __builtin_amdgcn_s_setprio(0);
      __builtin_amdgcn_s_barrier();
    }
  }

  const int crow = m0 + wm * 128 + quad * 4;
  const int ccol = n0 + wn * 48 + l15;
#pragma unroll
  for (int mi = 0; mi < 8; ++mi)
#pragma unroll
    for (int ni = 0; ni < 3; ++ni)
#pragma unroll
      for (int r = 0; r < 4; ++r)
        C[(size_t)(crow + mi * 16 + r) * QKV_N + ccol + ni * 16] =
            __float2bfloat16(acc[mi][ni][r]);
}

// ---------------------------------------------------------------------------
// Epilogue: reads C[2048][6144] bf16 (L3-resident). Verified R1.
// ---------------------------------------------------------------------------
__global__ __launch_bounds__(256)
void qkv_epilogue(const __hip_bfloat16* __restrict__ C,
                  const float* __restrict__ q_scale, const float* __restrict__ k_scale,
                  const float* __restrict__ pe,
                  __hip_bfloat16* __restrict__ Qb, __hip_bfloat16* __restrict__ Kb,
                  __hip_bfloat16* __restrict__ Vt) {
  const int bid = blockIdx.x;
  const int t = threadIdx.x;
  if (bid < 512) {
    const int sec = bid >> 8;          // 0 = q, 1 = k
    const int h   = (bid >> 4) & 15;
    const int rb  = bid & 15;          // 16 row-blocks of 128
    const float* scale = sec ? k_scale : q_scale;
    const float qmul = sec ? 1.0f : 0.08838834764831845f;
    __hip_bfloat16* dst = sec ? Kb : Qb;

    const int row = t >> 1, half = t & 1;
    const int l = rb * 128 + row;
    const __hip_bfloat16* grow = C + (size_t)l * TDIM + sec * DIM + h * HD + half * 64;

    float ss = 0.f;
#pragma unroll
    for (int c8 = 0; c8 < 64; c8 += 8) {
      short8 v8 = *(const short8*)(grow + c8);
#pragma unroll
      for (int j = 0; j < 8; ++j) { float f = bits2f(v8[j]); ss += f * f; }
    }
    ss += __shfl_xor(ss, 1);
    const float rrms = rsqrtf(ss * (1.f / 128.f) + 1e-6f);

    const float* perow = pe + (size_t)l * 256 + half * 128;
    __hip_bfloat16* drow = dst + ((size_t)h * L_SEQ + l) * HD + half * 64;

#pragma unroll
    for (int c8 = 0; c8 < 64; c8 += 8) {
      short8 v8 = *(const short8*)(grow + c8);
      float f[8];
#pragma unroll
      for (int j = 0; j < 8; ++j)
        f[j] = bits2f(v8[j]) * rrms * scale[half * 64 + c8 + j];
      short8 o;
#pragma unroll
      for (int p = 0; p < 4; ++p) {
        float4 pp = *(const float4*)(perow + c8 * 2 + p * 4);
        float e = f[2 * p], od = f[2 * p + 1];
        o[2 * p]     = bf16bits((pp.x * e + pp.y * od) * qmul);
        o[2 * p + 1] = bf16bits((pp.z * e + pp.w * od) * qmul);
      }
      *(short8*)(drow + c8) = o;
    }
  } else {
    __shared__ short Tt[128 * 72];
    const int vb = bid - 512;
    const int h = vb >> 5, lb = vb & 31;
    const int l0 = lb * 64;
#pragma unroll
    for (int k = 0; k < 4; ++k) {
      int idx = t + k * 256;
      int row = idx >> 4, c = idx & 15;
      short8 v = *(const short8*)(C + (size_t)(l0 + row) * TDIM + 2 * DIM + h * HD + c * 8);
#pragma unroll
      for (int j = 0; j < 8; ++j) Tt[(c * 8 + j) * 72 + row] = v[j];
    }
    __syncthreads();
    const int d = t >> 1, lh = t & 1;
    __hip_bfloat16* vrow = Vt + ((size_t)h * HD + d) * L_SEQ + l0 + lh * 32;
#pragma unroll
    for (int k = 0; k < 4; ++k) {
      short8 o = *(const short8*)&Tt[d * 72 + lh * 32 + k * 8];
      *(short8*)(vrow + k * 8) = o;
    }
  }
}

// ---------------------------------------------------------------------------
// Proj GEMM (verified R5): deep-ring 128x128, 256 blocks = 1/CU.
// ---------------------------------------------------------------------------
#define PJ_N 2048
#define PJ_K 2048

__global__ __launch_bounds__(256, 2)
void gemm_proj_128(const __hip_bfloat16* __restrict__ A,
                   const __hip_bfloat16* __restrict__ B,
                   const float* __restrict__ bias, float* __restrict__ C) {
  __shared__ __align__(16) char smem[65536];
  const int tid  = threadIdx.x;
  const int lane = tid & 63, w = tid >> 6;
  const int l15  = lane & 15, quad = lane >> 4;
  const int wm   = (w >> 1) * 64, wn = (w & 1) * 64;

  const int orig = blockIdx.x;
  const int c   = orig & 7;
  const int idx = orig >> 3;                // 0..31
  const int by  = (c >> 1) * 4 + (idx & 3); // 0..15
  const int bx  = (c & 1) * 8 + (idx >> 2); // 0..15
  const int m0 = by * 128, n0 = bx * 128;

  const int ar0 = tid >> 2,         aq0 = (tid & 3) ^ ((ar0 >> 1) & 3);
  const int ar1 = (256 + tid) >> 2, aq1 = (tid & 3) ^ ((ar1 >> 1) & 3);
  const __hip_bfloat16* pA0 = A + (size_t)(m0 + ar0) * PJ_K + aq0 * 8;
  const __hip_bfloat16* pA1 = A + (size_t)(m0 + ar1) * PJ_K + aq1 * 8;
  const __hip_bfloat16* pB0 = B + (size_t)(n0 + ar0) * PJ_K + aq0 * 8;
  const __hip_bfloat16* pB1 = B + (size_t)(n0 + ar1) * PJ_K + aq1 * 8;
  const int dst0 = w * 1024;

  f32x4 acc[4][4];
#pragma unroll
  for (int mi = 0; mi < 4; ++mi)
#pragma unroll
    for (int ni = 0; ni < 4; ++ni) acc[mi][ni] = (f32x4){0.f, 0.f, 0.f, 0.f};

  const int sq   = (l15 >> 1) & 3;
  const int aoff = ((wm + l15) * 32 + (quad ^ sq) * 8) * 2;
  const int boff = 8192 + ((wn + l15) * 32 + (quad ^ sq) * 8) * 2;

#pragma unroll
  for (int p = 0; p < 3; ++p) {
    char* Sp = smem + p * 16384;
    gl_lds16(pA0 + p * 32, Sp + dst0);
    gl_lds16(pA1 + p * 32, Sp + dst0 + 4096);
    gl_lds16(pB0 + p * 32, Sp + 8192 + dst0);
    gl_lds16(pB1 + p * 32, Sp + 8192 + dst0 + 4096);
  }
  asm volatile("s_waitcnt vmcnt(8)\n\ts_barrier" ::: "memory");

  for (int tb = 0; tb < 64; tb += 4) {
#pragma unroll
    for (int u = 0; u < 4; ++u) {
      const int t  = tb + u;
      const char* As = smem + u * 16384;
      const char* Bs = As;
      const int tn = (t + 3) & 63;
      char* Sn = smem + ((u + 3) & 3) * 16384;

      short8 a[4];
#pragma unroll
      for (int mi = 0; mi < 4; ++mi)
        a[mi] = *(const short8*)(As + aoff + mi * 1024);
      short8 b0 = *(const short8*)(Bs + boff);
      short8 b1 = *(const short8*)(Bs + boff + 1024);
      gl_lds16(pA0 + tn * 32, Sn + dst0);
      gl_lds16(pA1 + tn * 32, Sn + dst0 + 4096);
      __builtin_amdgcn_s_barrier();
      __builtin_amdgcn_s_setprio(1);
#pragma unroll
      for (int mi = 0; mi < 4; ++mi) {
        acc[mi][0] = __builtin_amdgcn_mfma_f32_16x16x32_bf16(a[mi], b0, acc[mi][0], 0, 0, 0);
        acc[mi][1] = __builtin_amdgcn_mfma_f32_16x16x32_bf16(a[mi], b1, acc[mi][1], 0, 0, 0);
      }
      __builtin_amdgcn_s_setprio(0);
      __builtin_amdgcn_s_barrier();

      short8 b2 = *(const short8*)(Bs + boff + 2048);
      short8 b3 = *(const short8*)(Bs + boff + 3072);
      gl_lds16(pB0 + tn * 32, Sn + 8192 + dst0);
      gl_lds16(pB1 + tn * 32, Sn + 8192 + dst0 + 4096);
      asm volatile("s_waitcnt vmcnt(8)\n\ts_barrier" ::: "memory");
      __builtin_amdgcn_s_setprio(1);
#pragma unroll
      for (int mi = 0; mi < 4; ++mi) {
        acc[mi][2] = __builtin_amdgcn_mfma_f32_16x16x32_bf16(a[mi], b2, acc[mi][2], 0, 0, 0);
        acc[mi][3] = __builtin_amdgcn_mfma_f32_16x16x32_bf16(a[mi], b3, acc[mi][3], 0, 0, 0);
      }
      __builtin_amdgcn_s_setprio(0);
      __builtin_amdgcn_s_barrier();
    }
  }

  const int crow = m0 + wm + quad * 4;
  const int ccol = n0 + wn + l15;
#pragma unroll
  for (int mi = 0; mi < 4; ++mi)
#pragma unroll
    for (int ni = 0; ni < 4; ++ni) {
      float bv = bias[ccol + ni * 16];
#pragma unroll
      for (int r = 0; r < 4; ++r)
        C[(size_t)(crow + mi * 16 + r) * PJ_N + ccol + ni * 16] =
            acc[mi][ni][r] + bv;
    }
}

// ---------------------------------------------------------------------------
// Flash attention v5: KVBLK=32 double-buffered 2-phase pipeline (T3-minimum):
// stage tile t+1 into buf^1 BEFORE computing tile t; one fused
// vmcnt(0)+barrier per tile. LDS total stays 32 KB (2 x (8K K + 8K V)) so
// residency is unchanged vs R6. Compute body = verified R4 one-ks tile
// (32x32 swapped-QK^T, lane-local softmax, cvt_pk+permlane P, O^T epilogue).
// ---------------------------------------------------------------------------
#define NZ 4
#define ZLEN (L_SEQ / NZ)

__global__ __launch_bounds__(256, 3)
void attn_mfma(const __hip_bfloat16* __restrict__ Qb,
               const __hip_bfloat16* __restrict__ Kb,
               const __hip_bfloat16* __restrict__ Vt,
               __hip_bfloat16* __restrict__ Opart, float2* __restrict__ ml) {
  const int orig = blockIdx.x;
  const int wg   = (orig & 7) * 128 + (orig >> 3);
  const int h    = wg >> 6;
  const int rem  = wg & 63;
  const int z    = rem >> 4;
  const int q0   = (rem & 15) * 128;
  const int t    = threadIdx.x;
  const int lane = t & 63, w = t >> 6;
  const int l31  = lane & 31;
  const int u    = lane >> 5;

  __shared__ __align__(16) char smem[32768];
  __hip_bfloat16* Ks = (__hip_bfloat16*)smem;            // [2][32][128]
  __hip_bfloat16* Vs = (__hip_bfloat16*)(smem + 16384);  // [2][128][32]

  const __hip_bfloat16* kbase = Kb + (size_t)h * L_SEQ * HD;
  const __hip_bfloat16* vbase = Vt + (size_t)h * HD * L_SEQ;

  // K: 32 rows x 256 B; LDS chunk c of row r holds k-chunk c^(r&7).
  // V: 128 rows x 64 B;  LDS chunk c of row r holds k-chunk c^(r&3).
  auto STAGE = [&](int kt_, int b_) {
    const int k0_ = z * ZLEN + kt_ * 32;
#pragma unroll
    for (int i = 0; i < 2; ++i) {
      int krow = w * 8 + i * 4 + (lane >> 4);
      int kch  = (lane & 15) ^ (krow & 7);
      gl_lds16(kbase + (size_t)(k0_ + krow) * HD + kch * 8,
               Ks + b_ * 4096 + (w * 8 + i * 4) * 128);
    }
#pragma unroll
    for (int i = 0; i < 2; ++i) {
      int vrow = w * 32 + i * 16 + (lane >> 2);
      int vch  = (lane & 3) ^ (vrow & 3);
      gl_lds16(vbase + (size_t)vrow * L_SEQ + k0_ + vch * 8,
               Vs + b_ * 4096 + (w * 32 + i * 16) * 32);
    }
  };

  short8 aq[8];
  {
    const __hip_bfloat16* qb = Qb + ((size_t)h * L_SEQ + q0 + w * 32 + l31) * HD + u * 8;
#pragma unroll
    for (int hh = 0; hh < 8; ++hh)
      aq[hh] = *(const short8*)(qb + hh * 16);
  }

  f32x16 o[4];
#pragma unroll
  for (int dt = 0; dt < 4; ++dt)
#pragma unroll
    for (int r = 0; r < 16; ++r) o[dt][r] = 0.f;
  float m_run = -1e30f, l_run = 0.f;

  const int NT = ZLEN / 32;   // 16
  STAGE(0, 0);
  asm volatile("s_waitcnt vmcnt(0)" ::: "memory");
  __builtin_amdgcn_s_barrier();

  for (int kt = 0; kt < NT; ++kt) {
    const int buf = kt & 1;
    if (kt + 1 < NT) STAGE(kt + 1, buf ^ 1);   // loads fly across compute

    const __hip_bfloat16* Kc = Ks + buf * 4096;
    const __hip_bfloat16* Vc = Vs + buf * 4096;

    // ---- QK^T: S[k = regs/u, q = l31] ----
    const char* krowp = (const char*)(Kc + l31 * 128);
    const int ksw = l31 & 7;
    f32x16 s;
#pragma unroll
    for (int r = 0; r < 16; ++r) s[r] = 0.f;
    __builtin_amdgcn_s_setprio(1);
#pragma unroll
    for (int hh = 0; hh < 8; ++hh) {
      short8 ak = *(const short8*)(krowp + ((hh * 2 + u) ^ ksw) * 16);
      s = __builtin_amdgcn_mfma_f32_32x32x16_bf16(ak, aq[hh], s, 0, 0, 0);
    }
    __builtin_amdgcn_s_setprio(0);

    // ---- softmax (verified R4 body) ----
    float rm = s[0];
#pragma unroll
    for (int r = 1; r < 16; ++r) rm = fmaxf(rm, s[r]);
    rm = fmaxf(rm, __shfl_xor(rm, 32));

    if (!__all(rm <= m_run + 8.f)) {
      float mnew = fmaxf(m_run, rm);
      float alpha = __expf(m_run - mnew);
      m_run = mnew;
      l_run *= alpha;
#pragma unroll
      for (int dt = 0; dt < 4; ++dt)
#pragma unroll
        for (int r = 0; r < 16; ++r) o[dt][r] *= alpha;
    }

    float sum = 0.f;
#pragma unroll
    for (int r = 0; r < 16; ++r) {
      float p = __expf(s[r] - m_run);
      s[r] = p;
      sum += p;
    }
    sum += __shfl_xor(sum, 32);
    l_run += sum;

    // ---- P -> bf16 B-fragments: 8 cvt_pk + 4 permlane32_swap ----
    unsigned int W0 = pack_bf16(s[0],  s[1]),  W1 = pack_bf16(s[2],  s[3]);
    unsigned int W2 = pack_bf16(s[4],  s[5]),  W3 = pack_bf16(s[6],  s[7]);
    unsigned int W4 = pack_bf16(s[8],  s[9]),  W5 = pack_bf16(s[10], s[11]);
    unsigned int W6 = pack_bf16(s[12], s[13]), W7 = pack_bf16(s[14], s[15]);
    asm("v_permlane32_swap_b32 %0, %1" : "+v"(W0), "+v"(W2));
    asm("v_permlane32_swap_b32 %0, %1" : "+v"(W1), "+v"(W3));
    asm("v_permlane32_swap_b32 %0, %1" : "+v"(W4), "+v"(W6));
    asm("v_permlane32_swap_b32 %0, %1" : "+v"(W5), "+v"(W7));
    u32x4 pb0 = {W0, W1, W2, W3};   // k 0..15
    u32x4 pb1 = {W4, W5, W6, W7};   // k 16..31
    short8 ap0 = *(short8*)&pb0;
    short8 ap1 = *(short8*)&pb1;

    // ---- PV: O^T[d, q] += V^T[d, k] * P[k, q] ----
    __builtin_amdgcn_s_setprio(1);
#pragma unroll
    for (int dt = 0; dt < 4; ++dt) {
      const int d = dt * 32 + l31;
      const char* vrowp = (const char*)(Vc + d * 32);
      const int vsw = d & 3;
      short8 av0 = *(const short8*)(vrowp + ((u) ^ vsw) * 16);
      o[dt] = __builtin_amdgcn_mfma_f32_32x32x16_bf16(av0, ap0, o[dt], 0, 0, 0);
      short8 av1 = *(const short8*)(vrowp + ((2 + u) ^ vsw) * 16);
      o[dt] = __builtin_amdgcn_mfma_f32_32x32x16_bf16(av1, ap1, o[dt], 0, 0, 0);
    }
    __builtin_amdgcn_s_setprio(0);

    // publish tile kt+1 (its loads had the whole compute phase to land)
    asm volatile("s_waitcnt vmcnt(0)" ::: "memory");
    __builtin_amdgcn_s_barrier();
  }

  // ---- epilogue: normalize (per-lane) and transpose via swizzled LDS ----
  const float linv = 1.f / l_run;
  char* Ot = smem + w * 8192;
  const int qsw = l31 & 7;
#pragma unroll
  for (int dt = 0; dt < 4; ++dt)
#pragma unroll
    for (int p = 0; p < 8; ++p) {
      unsigned int v = pack_bf16(o[dt][2 * p] * linv, o[dt][2 * p + 1] * linv);
      int dpair = dt * 16 + (p & 1) + (p >> 1) * 4 + 2 * u;
      *(unsigned int*)(Ot + l31 * 256 + ((dpair >> 2) ^ qsw) * 16 + (dpair & 3) * 4) = v;
    }
  __syncthreads();
  {
    const int qr = lane >> 1, half = lane & 1;
    const char* Orow = smem + w * 8192 + qr * 256;
    __hip_bfloat16* gout =
        Opart + ((size_t)(z * NH + h) * L_SEQ + q0 + w * 32 + qr) * HD;
#pragma unroll
    for (int c8 = 0; c8 < 8; ++c8) {
      int chunk = half * 8 + c8;
      short8 v = *(const short8*)(Orow + ((chunk ^ (qr & 7)) * 16));
      *(short8*)(gout + chunk * 8) = v;
    }
  }
  if (lane < 32) {
    size_t rb = (size_t)(z * NH + h) * L_SEQ + q0 + w * 32;
    ml[rb + l31] = make_float2(m_run, l_run);
  }
}

// ---------------------------------------------------------------------------
// Combine the four KV-split chunks. Verified R3.
// ---------------------------------------------------------------------------
__global__ __launch_bounds__(256)
void attn_combine4(const __hip_bfloat16* __restrict__ Opart,
                   const float2* __restrict__ ml,
                   __hip_bfloat16* __restrict__ out) {
  const int h  = blockIdx.y;
  const int q  = blockIdx.x * 16 + (threadIdx.x >> 4);
  const int d8 = (threadIdx.x & 15) * 8;
  size_t idx[NZ];
  float2 a[NZ];
#pragma unroll
  for (int zz = 0; zz < NZ; ++zz) {
    idx[zz] = ((size_t)zz * NH + h) * L_SEQ + q;
    a[zz] = ml[idx[zz]];
  }
  float M = fmaxf(fmaxf(a[0].x, a[1].x), fmaxf(a[2].x, a[3].x));
  float wz[NZ];
  float tot = 0.f;
#pragma unroll
  for (int zz = 0; zz < NZ; ++zz) {
    wz[zz] = __expf(a[zz].x - M) * a[zz].y;
    tot += wz[zz];
  }
  float inv = 1.f / tot;
  float acc[8] = {0.f, 0.f, 0.f, 0.f, 0.f, 0.f, 0.f, 0.f};
#pragma unroll
  for (int zz = 0; zz < NZ; ++zz) {
    short8 ov = *(const short8*)&Opart[idx[zz] * HD + d8];
#pragma unroll
    for (int j = 0; j < 8; ++j) acc[j] += wz[zz] * bits2f(ov[j]);
  }
  short8 r;
#pragma unroll
  for (int j = 0; j < 8; ++j) r[j] = bf16bits(acc[j] * inv);
  *(short8*)&out[(size_t)q * DIM + h * HD + d8] = r;
}

// ---------------------------------------------------------------------------
extern "C" void kernel_launch(void* const* d_in, const int* in_sizes, int n_in,
                              void* d_out, int out_size, void* d_ws, size_t ws_size,
                              hipStream_t stream) {
  const float* x       = (const float*)d_in[0];
  const float* pe      = (const float*)d_in[1];
  const float* qkv_w   = (const float*)d_in[2];
  const float* q_scale = (const float*)d_in[3];
  const float* k_scale = (const float*)d_in[4];
  const float* proj_w  = (const float*)d_in[5];
  const float* proj_b  = (const float*)d_in[6];
  float* out = (float*)d_out;

  // Workspace (67,108,864 B), phase-disjoint reuse (verified R6):
  //  p1 cast3+gemm: xb [0,8.4M) | wb [8.4,33.6M) | Cq [33.6,58.8M) | pwb [58.8,67.1M)
  //  p2 epilogue:   reads Cq; Qb [0,8.4M) Kb [8.4,16.8M) Vt [16.8,25.2M)
  //  p3 attn z=4:   Opart [25.2,58.8M), ml -> d_out scratch
  //  p4 combine:    attn_out [0,8.4M) (over dead Qb)
  //  p5 proj:       reads attn_out + pwb; writes out (overwrites ml scratch)
  char* base = (char*)d_ws;
  __hip_bfloat16* xb       = (__hip_bfloat16*)base;
  __hip_bfloat16* wb       = (__hip_bfloat16*)(base + 8388608);
  __hip_bfloat16* Cq       = (__hip_bfloat16*)(base + 33554432);
  __hip_bfloat16* pwb      = (__hip_bfloat16*)(base + 58720256);
  __hip_bfloat16* Qb       = (__hip_bfloat16*)base;
  __hip_bfloat16* Kb       = (__hip_bfloat16*)(base + 8388608);
  __hip_bfloat16* Vt       = (__hip_bfloat16*)(base + 16777216);
  __hip_bfloat16* Opart    = (__hip_bfloat16*)(base + 25165824);
  float2*         ml       = (float2*)d_out;
  __hip_bfloat16* attn_out = (__hip_bfloat16*)base;

  static bool attr_done = false;
  if (!attr_done) {
    hipFuncSetAttribute((const void*)gemm_qkv_256,
                        hipFuncAttributeMaxDynamicSharedMemorySize, 131072);
    attr_done = true;
  }

  cast3_bf16<<<dim3((2 * DIM * DIM + TDIM * DIM) / (256 * 8)), 256, 0, stream>>>(
      x, xb, qkv_w, wb, proj_w, pwb);

  gemm_qkv_256<<<dim3(256), 512, 114688, stream>>>(xb, wb, Cq);

  qkv_epilogue<<<dim3(1024), 256, 0, stream>>>(Cq, q_scale, k_scale, pe, Qb, Kb, Vt);

  attn_mfma<<<dim3(NZ * NH * (L_SEQ / 128)), 256, 0, stream>>>(Qb, Kb, Vt, Opart, ml);

  attn_combine4<<<dim3(L_SEQ / 16, NH), 256, 0, stream>>>(Opart, ml, attn_out);

  gemm_proj_128<<<dim3(256), 256, 0, stream>>>(attn_out, pwb, proj_b, out);
}